// Round 2
// baseline (406.954 us; speedup 1.0000x reference)
//
#include <hip/hip_runtime.h>
#include <math.h>

#define NEI 15
#define ROWSTRIDE 16   // pad neighbor rows to 16 ints for int4 loads

// Compile-time component select from 4 int4s (K must be a constant after unroll)
#define GET16(n0, n1, n2, n3, K)                                   \
    ((K) < 8                                                       \
         ? ((K) < 4                                                \
                ? ((K) == 0 ? (n0).x : (K) == 1 ? (n0).y           \
                                : (K) == 2 ? (n0).z : (n0).w)      \
                : ((K) == 4 ? (n1).x : (K) == 5 ? (n1).y           \
                                : (K) == 6 ? (n1).z : (n1).w))     \
         : ((K) < 12                                               \
                ? ((K) == 8 ? (n2).x : (K) == 9 ? (n2).y           \
                                : (K) == 10 ? (n2).z : (n2).w)     \
                : ((K) == 12 ? (n3).x : (K) == 13 ? (n3).y         \
                                : (K) == 14 ? (n3).z : (n3).w)))

// ---------------------------------------------------------------------------
// Kernel 1: one wave per row. Stream the row as float4; wave prefix-sum of
// per-lane nonzero counts gives each nonzero its rank -> neighbors written
// directly in ascending column order (no atomics, no sort, no memset).
// ---------------------------------------------------------------------------
__global__ void find_nb_kernel(const float* __restrict__ A,
                               int* __restrict__ nb, int N) {
    const int wavesPerBlock = blockDim.x >> 6;
    const int row = blockIdx.x * wavesPerBlock + (threadIdx.x >> 6);
    const int lane = threadIdx.x & 63;
    if (row >= N) return;                       // wave-uniform
    const float4* rowp = reinterpret_cast<const float4*>(A + (long long)row * N);
    const int n4 = N >> 2;
    int count = 0;
    for (int c0 = 0; c0 < n4; c0 += 64) {
        const int idx = c0 + lane;
        float4 v = make_float4(0.f, 0.f, 0.f, 0.f);
        if (idx < n4) v = rowp[idx];
        const int nz = (v.x != 0.f) + (v.y != 0.f) + (v.z != 0.f) + (v.w != 0.f);
        int pre = nz;
        #pragma unroll
        for (int d = 1; d < 64; d <<= 1) {
            const int o = __shfl_up(pre, d);
            if (lane >= d) pre += o;
        }
        const int excl = pre - nz;
        const int tot = __shfl(pre, 63);
        int p = count + excl;
        const float vals[4] = {v.x, v.y, v.z, v.w};
        #pragma unroll
        for (int q = 0; q < 4; ++q) {
            if (vals[q] != 0.f) {
                if (p < NEI) nb[row * ROWSTRIDE + p] = (idx << 2) + q;
                ++p;
            }
        }
        count += tot;
    }
    // tail columns if N % 4 != 0
    const int base = n4 << 2;
    const int rem = N - base;
    if (rem > 0) {
        float v = 0.f;
        if (lane < rem) v = A[(long long)row * N + base + lane];
        const int nz = (v != 0.f) ? 1 : 0;
        int pre = nz;
        #pragma unroll
        for (int d = 1; d < 64; d <<= 1) {
            const int o = __shfl_up(pre, d);
            if (lane >= d) pre += o;
        }
        const int excl = pre - nz;
        if (v != 0.f) {
            const int p = count + excl;
            if (p < NEI) nb[row * ROWSTRIDE + p] = base + lane;
        }
    }
}

// ---------------------------------------------------------------------------
// Kernel 2: count triangles per (i, j) pair. tid = i*15 + j.
// a = nb[i][j]; if a > i, count k > j with b = nb[i][k] adjacent to a.
// All inner indices compile-time via full unroll (no scratch arrays).
// ---------------------------------------------------------------------------
__global__ void count_tri_kernel(const int* __restrict__ nb,
                                 int* __restrict__ cnt2, int N) {
    const int tid = blockIdx.x * blockDim.x + threadIdx.x;
    const int M = N * NEI;
    if (tid >= M) return;
    const int i = tid / NEI;
    const int j = tid - i * NEI;
    const int a = nb[i * ROWSTRIDE + j];
    int c = 0;
    if (a > i) {
        const int4* np = reinterpret_cast<const int4*>(nb + a * ROWSTRIDE);
        const int4 n0 = np[0], n1 = np[1], n2 = np[2], n3 = np[3];
        const int4* vp = reinterpret_cast<const int4*>(nb + i * ROWSTRIDE);
        const int4 w0 = vp[0], w1 = vp[1], w2 = vp[2], w3 = vp[3];
        #pragma unroll
        for (int k = 1; k < NEI; ++k) {
            if (k > j) {
                const int b = GET16(w0, w1, w2, w3, k);
                const bool adj =
                    (n0.x == b) || (n0.y == b) || (n0.z == b) || (n0.w == b) ||
                    (n1.x == b) || (n1.y == b) || (n1.z == b) || (n1.w == b) ||
                    (n2.x == b) || (n2.y == b) || (n2.z == b) || (n2.w == b) ||
                    (n3.x == b) || (n3.y == b) || (n3.z == b);
                c += adj ? 1 : 0;
            }
        }
    }
    cnt2[tid] = c;
}

// ---------------------------------------------------------------------------
// Kernel 3: single-block exclusive prefix sum over cnt2[0..M) -> offs2.
// ---------------------------------------------------------------------------
__global__ void scan_kernel(const int* __restrict__ cnt2,
                            int* __restrict__ offs2, int M) {
    __shared__ int partial[1024];
    const int tid = threadIdx.x;
    const int per = (M + 1023) / 1024;
    const int start = tid * per;
    int sum = 0;
    for (int q = 0; q < per; ++q) {
        const int idx = start + q;
        if (idx < M) sum += cnt2[idx];
    }
    partial[tid] = sum;
    __syncthreads();
    for (int d = 1; d < 1024; d <<= 1) {
        const int mine  = partial[tid];
        const int other = (tid >= d) ? partial[tid - d] : 0;
        __syncthreads();
        partial[tid] = mine + other;
        __syncthreads();
    }
    int run = (tid == 0) ? 0 : partial[tid - 1];
    for (int q = 0; q < per; ++q) {
        const int idx = start + q;
        if (idx < M) { offs2[idx] = run; run += cnt2[idx]; }
    }
}

// ---------------------------------------------------------------------------
// Kernel 4: emit triangles per (i, j) pair at offs2[tid], k ascending.
// Global order (i asc, j asc, k asc) == unique's row-lexicographic order.
// ---------------------------------------------------------------------------
__global__ void emit_tri_kernel(const int* __restrict__ nb,
                                const int* __restrict__ offs2,
                                int* __restrict__ out, int N) {
    const int tid = blockIdx.x * blockDim.x + threadIdx.x;
    const int M = N * NEI;
    if (tid >= M) return;
    const int i = tid / NEI;
    const int j = tid - i * NEI;
    const int a = nb[i * ROWSTRIDE + j];
    if (a <= i) return;
    const int4* np = reinterpret_cast<const int4*>(nb + a * ROWSTRIDE);
    const int4 n0 = np[0], n1 = np[1], n2 = np[2], n3 = np[3];
    const int4* vp = reinterpret_cast<const int4*>(nb + i * ROWSTRIDE);
    const int4 w0 = vp[0], w1 = vp[1], w2 = vp[2], w3 = vp[3];
    int pos = offs2[tid];
    #pragma unroll
    for (int k = 1; k < NEI; ++k) {
        if (k > j) {
            const int b = GET16(w0, w1, w2, w3, k);
            const bool adj =
                (n0.x == b) || (n0.y == b) || (n0.z == b) || (n0.w == b) ||
                (n1.x == b) || (n1.y == b) || (n1.z == b) || (n1.w == b) ||
                (n2.x == b) || (n2.y == b) || (n2.z == b) || (n2.w == b) ||
                (n3.x == b) || (n3.y == b) || (n3.z == b);
            if (adj) {
                out[3 * pos + 0] = i;
                out[3 * pos + 1] = a;
                out[3 * pos + 2] = b;
                ++pos;
            }
        }
    }
}

extern "C" void kernel_launch(void* const* d_in, const int* in_sizes, int n_in,
                              void* d_out, int out_size, void* d_ws, size_t ws_size,
                              hipStream_t stream) {
    const float* A = (const float*)d_in[0];
    const long long total = (long long)in_sizes[0];
    const int N = (int)llround(sqrt((double)total));
    const int M = N * NEI;
    const int Mpad = ((M + 1023) / 1024) * 1024;

    int* ws = (int*)d_ws;
    // Workspace (ints): nb[N*16] | cnt2[Mpad] | offs2[Mpad]
    int* w_nb    = ws;
    int* w_cnt2  = ws + N * ROWSTRIDE;
    int* w_offs2 = ws + N * ROWSTRIDE + Mpad;

    int* out = (int*)d_out;

    // 1) find neighbors, written in ascending column order (one wave per row)
    {
        const int threads = 256;                 // 4 waves -> 4 rows per block
        const int blocks = (N + 3) / 4;
        find_nb_kernel<<<blocks, threads, 0, stream>>>(A, w_nb, N);
    }
    // 2) count per (i, j)
    {
        const int threads = 256;
        const int blocks = (M + threads - 1) / threads;
        count_tri_kernel<<<blocks, threads, 0, stream>>>(w_nb, w_cnt2, N);
    }
    // 3) exclusive scan
    scan_kernel<<<1, 1024, 0, stream>>>(w_cnt2, w_offs2, M);
    // 4) emit
    {
        const int threads = 256;
        const int blocks = (M + threads - 1) / threads;
        emit_tri_kernel<<<blocks, threads, 0, stream>>>(w_nb, w_offs2, out, N);
    }
}

// Round 3
// 114.283 us; speedup vs baseline: 3.5609x; 3.5609x over previous
//
#include <hip/hip_runtime.h>
#include <math.h>

#define NEI 15
#define ROWSTRIDE 16     // pad neighbor rows to 16 ints for int4 loads
#define CHUNK 2048       // elements per scan1 block (256 threads x 8)

// Compile-time component select from 4 int4s (K must be a constant after unroll)
#define GET16(n0, n1, n2, n3, K)                                   \
    ((K) < 8                                                       \
         ? ((K) < 4                                                \
                ? ((K) == 0 ? (n0).x : (K) == 1 ? (n0).y           \
                                : (K) == 2 ? (n0).z : (n0).w)      \
                : ((K) == 4 ? (n1).x : (K) == 5 ? (n1).y           \
                                : (K) == 6 ? (n1).z : (n1).w))     \
         : ((K) < 12                                               \
                ? ((K) == 8 ? (n2).x : (K) == 9 ? (n2).y           \
                                : (K) == 10 ? (n2).z : (n2).w)     \
                : ((K) == 12 ? (n3).x : (K) == 13 ? (n3).y         \
                                : (K) == 14 ? (n3).z : (n3).w)))

// ---------------------------------------------------------------------------
// Kernel 1: one wave per row. Stream the row as float4; wave prefix-sum of
// per-lane nonzero counts gives each nonzero its rank -> neighbors written
// directly in ascending column order (no atomics, no sort, no memset).
// ---------------------------------------------------------------------------
__global__ void find_nb_kernel(const float* __restrict__ A,
                               int* __restrict__ nb, int N) {
    const int wavesPerBlock = blockDim.x >> 6;
    const int row = blockIdx.x * wavesPerBlock + (threadIdx.x >> 6);
    const int lane = threadIdx.x & 63;
    if (row >= N) return;                       // wave-uniform
    const float4* rowp = reinterpret_cast<const float4*>(A + (long long)row * N);
    const int n4 = N >> 2;
    int count = 0;
    for (int c0 = 0; c0 < n4; c0 += 64) {
        const int idx = c0 + lane;
        float4 v = make_float4(0.f, 0.f, 0.f, 0.f);
        if (idx < n4) v = rowp[idx];
        const int nz = (v.x != 0.f) + (v.y != 0.f) + (v.z != 0.f) + (v.w != 0.f);
        int pre = nz;
        #pragma unroll
        for (int d = 1; d < 64; d <<= 1) {
            const int o = __shfl_up(pre, d);
            if (lane >= d) pre += o;
        }
        const int excl = pre - nz;
        const int tot = __shfl(pre, 63);
        int p = count + excl;
        const float vals[4] = {v.x, v.y, v.z, v.w};
        #pragma unroll
        for (int q = 0; q < 4; ++q) {
            if (vals[q] != 0.f) {
                if (p < NEI) nb[row * ROWSTRIDE + p] = (idx << 2) + q;
                ++p;
            }
        }
        count += tot;
    }
    // tail columns if N % 4 != 0
    const int base = n4 << 2;
    const int rem = N - base;
    if (rem > 0) {
        float v = 0.f;
        if (lane < rem) v = A[(long long)row * N + base + lane];
        const int nz = (v != 0.f) ? 1 : 0;
        int pre = nz;
        #pragma unroll
        for (int d = 1; d < 64; d <<= 1) {
            const int o = __shfl_up(pre, d);
            if (lane >= d) pre += o;
        }
        const int excl = pre - nz;
        if (v != 0.f) {
            const int p = count + excl;
            if (p < NEI) nb[row * ROWSTRIDE + p] = base + lane;
        }
    }
}

// ---------------------------------------------------------------------------
// Kernel 2: count triangles per (i, j) pair. tid = i*15 + j.
// ---------------------------------------------------------------------------
__global__ void count_tri_kernel(const int* __restrict__ nb,
                                 int* __restrict__ cnt2, int N) {
    const int tid = blockIdx.x * blockDim.x + threadIdx.x;
    const int M = N * NEI;
    if (tid >= M) return;
    const int i = tid / NEI;
    const int j = tid - i * NEI;
    const int a = nb[i * ROWSTRIDE + j];
    int c = 0;
    if (a > i) {
        const int4* np = reinterpret_cast<const int4*>(nb + a * ROWSTRIDE);
        const int4 n0 = np[0], n1 = np[1], n2 = np[2], n3 = np[3];
        const int4* vp = reinterpret_cast<const int4*>(nb + i * ROWSTRIDE);
        const int4 w0 = vp[0], w1 = vp[1], w2 = vp[2], w3 = vp[3];
        #pragma unroll
        for (int k = 1; k < NEI; ++k) {
            if (k > j) {
                const int b = GET16(w0, w1, w2, w3, k);
                const bool adj =
                    (n0.x == b) || (n0.y == b) || (n0.z == b) || (n0.w == b) ||
                    (n1.x == b) || (n1.y == b) || (n1.z == b) || (n1.w == b) ||
                    (n2.x == b) || (n2.y == b) || (n2.z == b) || (n2.w == b) ||
                    (n3.x == b) || (n3.y == b) || (n3.z == b);
                c += adj ? 1 : 0;
            }
        }
    }
    cnt2[tid] = c;
}

// ---------------------------------------------------------------------------
// Kernel 3a: per-chunk scan. Each block scans CHUNK elements of cnt2 into
// chunk-local exclusive offsets (offs2) and writes its chunk total.
// ---------------------------------------------------------------------------
__global__ void scan1_kernel(const int* __restrict__ cnt2,
                             int* __restrict__ offs2,
                             int* __restrict__ blockSums, int M) {
    __shared__ int partial[256];
    const int tid = threadIdx.x;
    const int base = blockIdx.x * CHUNK + tid * 8;
    int v[8];
    #pragma unroll
    for (int q = 0; q < 8; ++q) {
        const int idx = base + q;
        v[q] = (idx < M) ? cnt2[idx] : 0;
    }
    int s = 0;
    #pragma unroll
    for (int q = 0; q < 8; ++q) s += v[q];
    partial[tid] = s;
    __syncthreads();
    #pragma unroll
    for (int d = 1; d < 256; d <<= 1) {
        const int mine  = partial[tid];
        const int other = (tid >= d) ? partial[tid - d] : 0;
        __syncthreads();
        partial[tid] = mine + other;
        __syncthreads();
    }
    int run = (tid == 0) ? 0 : partial[tid - 1];
    #pragma unroll
    for (int q = 0; q < 8; ++q) {
        const int idx = base + q;
        if (idx < M) offs2[idx] = run;
        run += v[q];
    }
    if (tid == 255) blockSums[blockIdx.x] = partial[255];
}

// ---------------------------------------------------------------------------
// Kernel 3b: single small block scans the chunk totals -> exclusive offsets.
// ---------------------------------------------------------------------------
__global__ void scan2_kernel(const int* __restrict__ blockSums,
                             int* __restrict__ blockOffs, int B) {
    __shared__ int partial[256];
    const int tid = threadIdx.x;
    const int per = (B + 255) / 256;
    const int start = tid * per;
    int s = 0;
    for (int q = 0; q < per; ++q) {
        const int idx = start + q;
        if (idx < B) s += blockSums[idx];
    }
    partial[tid] = s;
    __syncthreads();
    #pragma unroll
    for (int d = 1; d < 256; d <<= 1) {
        const int mine  = partial[tid];
        const int other = (tid >= d) ? partial[tid - d] : 0;
        __syncthreads();
        partial[tid] = mine + other;
        __syncthreads();
    }
    int run = (tid == 0) ? 0 : partial[tid - 1];
    for (int q = 0; q < per; ++q) {
        const int idx = start + q;
        if (idx < B) { blockOffs[idx] = run; run += blockSums[idx]; }
    }
}

// ---------------------------------------------------------------------------
// Kernel 4: emit triangles per (i, j) pair at offs2[tid]+blockOffs[chunk].
// Global order (i asc, j asc, k asc) == unique's row-lexicographic order.
// ---------------------------------------------------------------------------
__global__ void emit_tri_kernel(const int* __restrict__ nb,
                                const int* __restrict__ offs2,
                                const int* __restrict__ blockOffs,
                                int* __restrict__ out, int N) {
    const int tid = blockIdx.x * blockDim.x + threadIdx.x;
    const int M = N * NEI;
    if (tid >= M) return;
    const int i = tid / NEI;
    const int j = tid - i * NEI;
    const int a = nb[i * ROWSTRIDE + j];
    if (a <= i) return;
    const int4* np = reinterpret_cast<const int4*>(nb + a * ROWSTRIDE);
    const int4 n0 = np[0], n1 = np[1], n2 = np[2], n3 = np[3];
    const int4* vp = reinterpret_cast<const int4*>(nb + i * ROWSTRIDE);
    const int4 w0 = vp[0], w1 = vp[1], w2 = vp[2], w3 = vp[3];
    int pos = offs2[tid] + blockOffs[tid / CHUNK];
    #pragma unroll
    for (int k = 1; k < NEI; ++k) {
        if (k > j) {
            const int b = GET16(w0, w1, w2, w3, k);
            const bool adj =
                (n0.x == b) || (n0.y == b) || (n0.z == b) || (n0.w == b) ||
                (n1.x == b) || (n1.y == b) || (n1.z == b) || (n1.w == b) ||
                (n2.x == b) || (n2.y == b) || (n2.z == b) || (n2.w == b) ||
                (n3.x == b) || (n3.y == b) || (n3.z == b);
            if (adj) {
                out[3 * pos + 0] = i;
                out[3 * pos + 1] = a;
                out[3 * pos + 2] = b;
                ++pos;
            }
        }
    }
}

extern "C" void kernel_launch(void* const* d_in, const int* in_sizes, int n_in,
                              void* d_out, int out_size, void* d_ws, size_t ws_size,
                              hipStream_t stream) {
    const float* A = (const float*)d_in[0];
    const long long total = (long long)in_sizes[0];
    const int N = (int)llround(sqrt((double)total));
    const int M = N * NEI;
    const int B = (M + CHUNK - 1) / CHUNK;      // scan chunks

    int* ws = (int*)d_ws;
    // Workspace (ints): nb[N*16] | cnt2[M] | offs2[M] | blockSums[B] | blockOffs[B]
    int* w_nb    = ws;
    int* w_cnt2  = ws + N * ROWSTRIDE;
    int* w_offs2 = w_cnt2 + M;
    int* w_bsum  = w_offs2 + M;
    int* w_boff  = w_bsum + B;

    int* out = (int*)d_out;

    // 1) find neighbors (written already sorted ascending; one wave per row)
    {
        const int threads = 256;                 // 4 waves -> 4 rows per block
        const int blocks = (N + 3) / 4;
        find_nb_kernel<<<blocks, threads, 0, stream>>>(A, w_nb, N);
    }
    // 2) count per (i, j)
    {
        const int threads = 256;
        const int blocks = (M + threads - 1) / threads;
        count_tri_kernel<<<blocks, threads, 0, stream>>>(w_nb, w_cnt2, N);
    }
    // 3) hierarchical exclusive scan
    scan1_kernel<<<B, 256, 0, stream>>>(w_cnt2, w_offs2, w_bsum, M);
    scan2_kernel<<<1, 256, 0, stream>>>(w_bsum, w_boff, B);
    // 4) emit
    {
        const int threads = 256;
        const int blocks = (M + threads - 1) / threads;
        emit_tri_kernel<<<blocks, threads, 0, stream>>>(w_nb, w_offs2, w_boff, out, N);
    }
}

// Round 4
// 101.165 us; speedup vs baseline: 4.0227x; 1.1297x over previous
//
#include <hip/hip_runtime.h>
#include <math.h>

#define NEI 15
#define ROWSTRIDE 16     // pad neighbor rows to 16 ints for int4 loads

// Compile-time component select from 4 int4s (K must be a constant after unroll)
#define GET16(n0, n1, n2, n3, K)                                   \
    ((K) < 8                                                       \
         ? ((K) < 4                                                \
                ? ((K) == 0 ? (n0).x : (K) == 1 ? (n0).y           \
                                : (K) == 2 ? (n0).z : (n0).w)      \
                : ((K) == 4 ? (n1).x : (K) == 5 ? (n1).y           \
                                : (K) == 6 ? (n1).z : (n1).w))     \
         : ((K) < 12                                               \
                ? ((K) == 8 ? (n2).x : (K) == 9 ? (n2).y           \
                                : (K) == 10 ? (n2).z : (n2).w)     \
                : ((K) == 12 ? (n3).x : (K) == 13 ? (n3).y         \
                                : (K) == 14 ? (n3).z : (n3).w)))

__device__ __forceinline__ int mbcnt64(unsigned long long m) {
    int c = __builtin_amdgcn_mbcnt_lo((unsigned)m, 0);
    c = __builtin_amdgcn_mbcnt_hi((unsigned)(m >> 32), c);
    return c;   // popcount of m over lanes strictly below this lane
}

// ---------------------------------------------------------------------------
// Kernel 1: one wave per row, 2 float4 loads in flight per iteration.
// Ballot + mbcnt ranking writes neighbors directly in ascending column order.
// ---------------------------------------------------------------------------
__global__ void find_nb_kernel(const float* __restrict__ A,
                               int* __restrict__ nb, int N) {
    const int wavesPerBlock = blockDim.x >> 6;
    const int row = blockIdx.x * wavesPerBlock + (threadIdx.x >> 6);
    const int lane = threadIdx.x & 63;
    if (row >= N) return;                       // wave-uniform
    const float4* rowp = reinterpret_cast<const float4*>(A + (long long)row * N);
    const int n4 = N >> 2;
    int count = 0;

    for (int c0 = 0; c0 < n4; c0 += 128) {
        const int idx0 = c0 + lane;
        const int idx1 = c0 + 64 + lane;
        float4 v0 = make_float4(0.f, 0.f, 0.f, 0.f);
        float4 v1 = make_float4(0.f, 0.f, 0.f, 0.f);
        if (idx0 < n4) v0 = rowp[idx0];
        if (idx1 < n4) v1 = rowp[idx1];

        #pragma unroll
        for (int half = 0; half < 2; ++half) {
            const float4 v = half ? v1 : v0;
            const int idx = half ? idx1 : idx0;
            const unsigned long long m0 = __ballot(v.x != 0.f);
            const unsigned long long m1 = __ballot(v.y != 0.f);
            const unsigned long long m2 = __ballot(v.z != 0.f);
            const unsigned long long m3 = __ballot(v.w != 0.f);
            if ((m0 | m1 | m2 | m3) != 0ull) {
                const int below = mbcnt64(m0) + mbcnt64(m1) + mbcnt64(m2) + mbcnt64(m3);
                const int b0 = (int)((m0 >> lane) & 1ull);
                const int b1 = (int)((m1 >> lane) & 1ull);
                const int b2 = (int)((m2 >> lane) & 1ull);
                const int base = count + below;
                if (v.x != 0.f) { const int p = base;                if (p < NEI) nb[row * ROWSTRIDE + p] = (idx << 2) + 0; }
                if (v.y != 0.f) { const int p = base + b0;           if (p < NEI) nb[row * ROWSTRIDE + p] = (idx << 2) + 1; }
                if (v.z != 0.f) { const int p = base + b0 + b1;      if (p < NEI) nb[row * ROWSTRIDE + p] = (idx << 2) + 2; }
                if (v.w != 0.f) { const int p = base + b0 + b1 + b2; if (p < NEI) nb[row * ROWSTRIDE + p] = (idx << 2) + 3; }
                count += __popcll(m0) + __popcll(m1) + __popcll(m2) + __popcll(m3);
            }
        }
    }
    // tail columns if N % 4 != 0
    const int base4 = n4 << 2;
    const int rem = N - base4;
    if (rem > 0) {
        float v = 0.f;
        if (lane < rem) v = A[(long long)row * N + base4 + lane];
        const unsigned long long m = __ballot(v != 0.f);
        if (v != 0.f) {
            const int p = count + mbcnt64(m);
            if (p < NEI) nb[row * ROWSTRIDE + p] = base4 + lane;
        }
    }
}

// ---------------------------------------------------------------------------
// Kernel 2: per-(i,j) triangle count + 15-bit adjacency mask, fused with the
// per-block (256-wide) exclusive scan. offs2 is block-local; blockSums[b] is
// the block total.
// ---------------------------------------------------------------------------
__global__ void count_tri_kernel(const int* __restrict__ nb,
                                 int* __restrict__ mask2,
                                 int* __restrict__ offs2,
                                 int* __restrict__ blockSums, int N) {
    __shared__ int partial[256];
    const int tid = blockIdx.x * 256 + threadIdx.x;
    const int M = N * NEI;
    int c = 0, mask = 0;
    if (tid < M) {
        const int i = tid / NEI;
        const int j = tid - i * NEI;
        const int a = nb[i * ROWSTRIDE + j];
        if (a > i) {
            const int4* np = reinterpret_cast<const int4*>(nb + a * ROWSTRIDE);
            const int4 n0 = np[0], n1 = np[1], n2 = np[2], n3 = np[3];
            const int4* vp = reinterpret_cast<const int4*>(nb + i * ROWSTRIDE);
            const int4 w0 = vp[0], w1 = vp[1], w2 = vp[2], w3 = vp[3];
            #pragma unroll
            for (int k = 1; k < NEI; ++k) {
                if (k > j) {
                    const int b = GET16(w0, w1, w2, w3, k);
                    const bool adj =
                        (n0.x == b) || (n0.y == b) || (n0.z == b) || (n0.w == b) ||
                        (n1.x == b) || (n1.y == b) || (n1.z == b) || (n1.w == b) ||
                        (n2.x == b) || (n2.y == b) || (n2.z == b) || (n2.w == b) ||
                        (n3.x == b) || (n3.y == b) || (n3.z == b);
                    if (adj) { mask |= (1 << k); ++c; }
                }
            }
        }
        mask2[tid] = mask;
    }
    partial[threadIdx.x] = c;
    __syncthreads();
    #pragma unroll
    for (int d = 1; d < 256; d <<= 1) {
        const int mine  = partial[threadIdx.x];
        const int other = (threadIdx.x >= d) ? partial[threadIdx.x - d] : 0;
        __syncthreads();
        partial[threadIdx.x] = mine + other;
        __syncthreads();
    }
    if (tid < M) offs2[tid] = (threadIdx.x == 0) ? 0 : partial[threadIdx.x - 1];
    if (threadIdx.x == 255) blockSums[blockIdx.x] = partial[255];
}

// ---------------------------------------------------------------------------
// Kernel 3: single small block scans the block totals -> exclusive offsets.
// ---------------------------------------------------------------------------
__global__ void scan2_kernel(const int* __restrict__ blockSums,
                             int* __restrict__ blockOffs, int B) {
    __shared__ int partial[256];
    const int tid = threadIdx.x;
    const int per = (B + 255) / 256;
    const int start = tid * per;
    int s = 0;
    for (int q = 0; q < per; ++q) {
        const int idx = start + q;
        if (idx < B) s += blockSums[idx];
    }
    partial[tid] = s;
    __syncthreads();
    #pragma unroll
    for (int d = 1; d < 256; d <<= 1) {
        const int mine  = partial[tid];
        const int other = (tid >= d) ? partial[tid - d] : 0;
        __syncthreads();
        partial[tid] = mine + other;
        __syncthreads();
    }
    int run = (tid == 0) ? 0 : partial[tid - 1];
    for (int q = 0; q < per; ++q) {
        const int idx = start + q;
        if (idx < B) { blockOffs[idx] = run; run += blockSums[idx]; }
    }
}

// ---------------------------------------------------------------------------
// Kernel 4: emit triangles by decoding the adjacency mask (no re-compare,
// no row-a gather). Global order (i asc, j asc, k asc) == lexicographic.
// ---------------------------------------------------------------------------
__global__ void emit_tri_kernel(const int* __restrict__ nb,
                                const int* __restrict__ mask2,
                                const int* __restrict__ offs2,
                                const int* __restrict__ blockOffs,
                                int* __restrict__ out, int N) {
    const int tid = blockIdx.x * blockDim.x + threadIdx.x;
    const int M = N * NEI;
    if (tid >= M) return;
    const int mask = mask2[tid];
    if (mask == 0) return;
    const int i = tid / NEI;
    const int j = tid - i * NEI;
    const int a = nb[i * ROWSTRIDE + j];
    const int4* vp = reinterpret_cast<const int4*>(nb + i * ROWSTRIDE);
    const int4 w0 = vp[0], w1 = vp[1], w2 = vp[2], w3 = vp[3];
    int pos = offs2[tid] + blockOffs[tid >> 8];
    #pragma unroll
    for (int k = 1; k < NEI; ++k) {
        if ((mask >> k) & 1) {
            const int b = GET16(w0, w1, w2, w3, k);
            out[3 * pos + 0] = i;
            out[3 * pos + 1] = a;
            out[3 * pos + 2] = b;
            ++pos;
        }
    }
}

extern "C" void kernel_launch(void* const* d_in, const int* in_sizes, int n_in,
                              void* d_out, int out_size, void* d_ws, size_t ws_size,
                              hipStream_t stream) {
    const float* A = (const float*)d_in[0];
    const long long total = (long long)in_sizes[0];
    const int N = (int)llround(sqrt((double)total));
    const int M = N * NEI;
    const int B = (M + 255) / 256;              // count/scan blocks

    int* ws = (int*)d_ws;
    // Workspace (ints): nb[N*16] | mask2[M] | offs2[M] | blockSums[B] | blockOffs[B]
    int* w_nb    = ws;
    int* w_mask2 = ws + N * ROWSTRIDE;
    int* w_offs2 = w_mask2 + M;
    int* w_bsum  = w_offs2 + M;
    int* w_boff  = w_bsum + B;

    int* out = (int*)d_out;

    // 1) find neighbors (written already sorted ascending; one wave per row)
    {
        const int threads = 256;                 // 4 waves -> 4 rows per block
        const int blocks = (N + 3) / 4;
        find_nb_kernel<<<blocks, threads, 0, stream>>>(A, w_nb, N);
    }
    // 2) count per (i,j) + adjacency masks + fused per-block scan
    count_tri_kernel<<<B, 256, 0, stream>>>(w_nb, w_mask2, w_offs2, w_bsum, N);
    // 3) scan of block totals
    scan2_kernel<<<1, 256, 0, stream>>>(w_bsum, w_boff, B);
    // 4) emit by mask decode
    {
        const int threads = 256;
        const int blocks = (M + threads - 1) / threads;
        emit_tri_kernel<<<blocks, threads, 0, stream>>>(w_nb, w_mask2, w_offs2, w_boff, out, N);
    }
}

// Round 5
// 76.891 us; speedup vs baseline: 5.2926x; 1.3157x over previous
//
#include <hip/hip_runtime.h>
#include <math.h>

#define NEI 15
#define ROWSTRIDE 16     // pad neighbor rows to 16 ints for int4 loads

typedef float f4 __attribute__((ext_vector_type(4)));

// Compile-time component select from 4 int4s (K must be a constant after unroll)
#define GET16(n0, n1, n2, n3, K)                                   \
    ((K) < 8                                                       \
         ? ((K) < 4                                                \
                ? ((K) == 0 ? (n0).x : (K) == 1 ? (n0).y           \
                                : (K) == 2 ? (n0).z : (n0).w)      \
                : ((K) == 4 ? (n1).x : (K) == 5 ? (n1).y           \
                                : (K) == 6 ? (n1).z : (n1).w))     \
         : ((K) < 12                                               \
                ? ((K) == 8 ? (n2).x : (K) == 9 ? (n2).y           \
                                : (K) == 10 ? (n2).z : (n2).w)     \
                : ((K) == 12 ? (n3).x : (K) == 13 ? (n3).y         \
                                : (K) == 14 ? (n3).z : (n3).w)))

__device__ __forceinline__ int mbcnt64(unsigned long long m) {
    int c = __builtin_amdgcn_mbcnt_lo((unsigned)m, 0);
    c = __builtin_amdgcn_mbcnt_hi((unsigned)(m >> 32), c);
    return c;   // popcount of m over lanes strictly below this lane
}

// ---------------------------------------------------------------------------
// Kernel 1: grid-strided waves over rows; 4 nontemporal float4 loads (4 KB)
// in flight per iteration; single combined ballot skips all-zero chunks.
// Ballot + mbcnt ranking writes neighbors in ascending column order.
// ---------------------------------------------------------------------------
__global__ void find_nb_kernel(const float* __restrict__ A,
                               int* __restrict__ nb, int N, int totalWaves) {
    const int wavesPerBlock = blockDim.x >> 6;
    const int waveId = blockIdx.x * wavesPerBlock + (threadIdx.x >> 6);
    const int lane = threadIdx.x & 63;
    const int n4 = N >> 2;

    for (int row = waveId; row < N; row += totalWaves) {
        const f4* rowp = reinterpret_cast<const f4*>(A + (long long)row * N);
        int count = 0;

        for (int c0 = 0; c0 < n4; c0 += 256) {
            const int i0 = c0 + lane;
            const int i1 = i0 + 64, i2 = i0 + 128, i3 = i0 + 192;
            f4 v0 = {0.f, 0.f, 0.f, 0.f}, v1 = {0.f, 0.f, 0.f, 0.f};
            f4 v2 = {0.f, 0.f, 0.f, 0.f}, v3 = {0.f, 0.f, 0.f, 0.f};
            if (i0 < n4) v0 = __builtin_nontemporal_load(&rowp[i0]);
            if (i1 < n4) v1 = __builtin_nontemporal_load(&rowp[i1]);
            if (i2 < n4) v2 = __builtin_nontemporal_load(&rowp[i2]);
            if (i3 < n4) v3 = __builtin_nontemporal_load(&rowp[i3]);

            const bool a0 = (v0.x != 0.f) || (v0.y != 0.f) || (v0.z != 0.f) || (v0.w != 0.f);
            const bool a1 = (v1.x != 0.f) || (v1.y != 0.f) || (v1.z != 0.f) || (v1.w != 0.f);
            const bool a2 = (v2.x != 0.f) || (v2.y != 0.f) || (v2.z != 0.f) || (v2.w != 0.f);
            const bool a3 = (v3.x != 0.f) || (v3.y != 0.f) || (v3.z != 0.f) || (v3.w != 0.f);
            if (__ballot(a0 || a1 || a2 || a3) == 0ull) continue;   // common path

            #pragma unroll
            for (int q = 0; q < 4; ++q) {
                const f4 v = (q == 0) ? v0 : (q == 1) ? v1 : (q == 2) ? v2 : v3;
                const int idx = c0 + q * 64 + lane;
                const unsigned long long m0 = __ballot(v.x != 0.f);
                const unsigned long long m1 = __ballot(v.y != 0.f);
                const unsigned long long m2 = __ballot(v.z != 0.f);
                const unsigned long long m3 = __ballot(v.w != 0.f);
                if ((m0 | m1 | m2 | m3) != 0ull) {
                    const int below = mbcnt64(m0) + mbcnt64(m1) + mbcnt64(m2) + mbcnt64(m3);
                    const int b0 = (int)((m0 >> lane) & 1ull);
                    const int b1 = (int)((m1 >> lane) & 1ull);
                    const int b2 = (int)((m2 >> lane) & 1ull);
                    const int base = count + below;
                    if (v.x != 0.f) { const int p = base;                if (p < NEI) nb[row * ROWSTRIDE + p] = (idx << 2) + 0; }
                    if (v.y != 0.f) { const int p = base + b0;           if (p < NEI) nb[row * ROWSTRIDE + p] = (idx << 2) + 1; }
                    if (v.z != 0.f) { const int p = base + b0 + b1;      if (p < NEI) nb[row * ROWSTRIDE + p] = (idx << 2) + 2; }
                    if (v.w != 0.f) { const int p = base + b0 + b1 + b2; if (p < NEI) nb[row * ROWSTRIDE + p] = (idx << 2) + 3; }
                    count += __popcll(m0) + __popcll(m1) + __popcll(m2) + __popcll(m3);
                }
            }
        }
        // tail columns if N % 4 != 0
        const int base4 = n4 << 2;
        const int rem = N - base4;
        if (rem > 0) {
            float v = 0.f;
            if (lane < rem) v = A[(long long)row * N + base4 + lane];
            const unsigned long long m = __ballot(v != 0.f);
            if (v != 0.f) {
                const int p = count + mbcnt64(m);
                if (p < NEI) nb[row * ROWSTRIDE + p] = base4 + lane;
            }
        }
    }
}

// ---------------------------------------------------------------------------
// Kernel 2: per-(i,j) triangle count + 15-bit adjacency mask, fused with the
// per-block (256-wide) exclusive scan.
// ---------------------------------------------------------------------------
__global__ void count_tri_kernel(const int* __restrict__ nb,
                                 int* __restrict__ mask2,
                                 int* __restrict__ offs2,
                                 int* __restrict__ blockSums, int N) {
    __shared__ int partial[256];
    const int tid = blockIdx.x * 256 + threadIdx.x;
    const int M = N * NEI;
    int c = 0, mask = 0;
    if (tid < M) {
        const int i = tid / NEI;
        const int j = tid - i * NEI;
        const int a = nb[i * ROWSTRIDE + j];
        if (a > i) {
            const int4* np = reinterpret_cast<const int4*>(nb + a * ROWSTRIDE);
            const int4 n0 = np[0], n1 = np[1], n2 = np[2], n3 = np[3];
            const int4* vp = reinterpret_cast<const int4*>(nb + i * ROWSTRIDE);
            const int4 w0 = vp[0], w1 = vp[1], w2 = vp[2], w3 = vp[3];
            #pragma unroll
            for (int k = 1; k < NEI; ++k) {
                if (k > j) {
                    const int b = GET16(w0, w1, w2, w3, k);
                    const bool adj =
                        (n0.x == b) || (n0.y == b) || (n0.z == b) || (n0.w == b) ||
                        (n1.x == b) || (n1.y == b) || (n1.z == b) || (n1.w == b) ||
                        (n2.x == b) || (n2.y == b) || (n2.z == b) || (n2.w == b) ||
                        (n3.x == b) || (n3.y == b) || (n3.z == b);
                    if (adj) { mask |= (1 << k); ++c; }
                }
            }
        }
        mask2[tid] = mask;
    }
    partial[threadIdx.x] = c;
    __syncthreads();
    #pragma unroll
    for (int d = 1; d < 256; d <<= 1) {
        const int mine  = partial[threadIdx.x];
        const int other = (threadIdx.x >= d) ? partial[threadIdx.x - d] : 0;
        __syncthreads();
        partial[threadIdx.x] = mine + other;
        __syncthreads();
    }
    if (tid < M) offs2[tid] = (threadIdx.x == 0) ? 0 : partial[threadIdx.x - 1];
    if (threadIdx.x == 255) blockSums[blockIdx.x] = partial[255];
}

// ---------------------------------------------------------------------------
// Kernel 3: single small block scans the block totals -> exclusive offsets.
// ---------------------------------------------------------------------------
__global__ void scan2_kernel(const int* __restrict__ blockSums,
                             int* __restrict__ blockOffs, int B) {
    __shared__ int partial[256];
    const int tid = threadIdx.x;
    const int per = (B + 255) / 256;
    const int start = tid * per;
    int s = 0;
    for (int q = 0; q < per; ++q) {
        const int idx = start + q;
        if (idx < B) s += blockSums[idx];
    }
    partial[tid] = s;
    __syncthreads();
    #pragma unroll
    for (int d = 1; d < 256; d <<= 1) {
        const int mine  = partial[tid];
        const int other = (tid >= d) ? partial[tid - d] : 0;
        __syncthreads();
        partial[tid] = mine + other;
        __syncthreads();
    }
    int run = (tid == 0) ? 0 : partial[tid - 1];
    for (int q = 0; q < per; ++q) {
        const int idx = start + q;
        if (idx < B) { blockOffs[idx] = run; run += blockSums[idx]; }
    }
}

// ---------------------------------------------------------------------------
// Kernel 4: emit triangles by decoding the adjacency mask.
// Global order (i asc, j asc, k asc) == unique's row-lexicographic order.
// ---------------------------------------------------------------------------
__global__ void emit_tri_kernel(const int* __restrict__ nb,
                                const int* __restrict__ mask2,
                                const int* __restrict__ offs2,
                                const int* __restrict__ blockOffs,
                                int* __restrict__ out, int N) {
    const int tid = blockIdx.x * blockDim.x + threadIdx.x;
    const int M = N * NEI;
    if (tid >= M) return;
    const int mask = mask2[tid];
    if (mask == 0) return;
    const int i = tid / NEI;
    const int j = tid - i * NEI;
    const int a = nb[i * ROWSTRIDE + j];
    const int4* vp = reinterpret_cast<const int4*>(nb + i * ROWSTRIDE);
    const int4 w0 = vp[0], w1 = vp[1], w2 = vp[2], w3 = vp[3];
    int pos = offs2[tid] + blockOffs[tid >> 8];
    #pragma unroll
    for (int k = 1; k < NEI; ++k) {
        if ((mask >> k) & 1) {
            const int b = GET16(w0, w1, w2, w3, k);
            out[3 * pos + 0] = i;
            out[3 * pos + 1] = a;
            out[3 * pos + 2] = b;
            ++pos;
        }
    }
}

extern "C" void kernel_launch(void* const* d_in, const int* in_sizes, int n_in,
                              void* d_out, int out_size, void* d_ws, size_t ws_size,
                              hipStream_t stream) {
    const float* A = (const float*)d_in[0];
    const long long total = (long long)in_sizes[0];
    const int N = (int)llround(sqrt((double)total));
    const int M = N * NEI;
    const int B = (M + 255) / 256;              // count/scan blocks

    int* ws = (int*)d_ws;
    // Workspace (ints): nb[N*16] | mask2[M] | offs2[M] | blockSums[B] | blockOffs[B]
    int* w_nb    = ws;
    int* w_mask2 = ws + N * ROWSTRIDE;
    int* w_offs2 = w_mask2 + M;
    int* w_bsum  = w_offs2 + M;
    int* w_boff  = w_bsum + B;

    int* out = (int*)d_out;

    // 1) find neighbors. Balanced grid: each wave handles an equal number of
    //    rows (2 for N=10000), all blocks resident -> no dispatch tail.
    {
        int totalWaves = (N <= 8192) ? N : (N + 1) / 2;
        const int blocks = (totalWaves + 3) / 4;
        totalWaves = blocks * 4;
        find_nb_kernel<<<blocks, 256, 0, stream>>>(A, w_nb, N, totalWaves);
    }
    // 2) count per (i,j) + adjacency masks + fused per-block scan
    count_tri_kernel<<<B, 256, 0, stream>>>(w_nb, w_mask2, w_offs2, w_bsum, N);
    // 3) scan of block totals
    scan2_kernel<<<1, 256, 0, stream>>>(w_bsum, w_boff, B);
    // 4) emit by mask decode
    {
        const int threads = 256;
        const int blocks = (M + threads - 1) / threads;
        emit_tri_kernel<<<blocks, threads, 0, stream>>>(w_nb, w_mask2, w_offs2, w_boff, out, N);
    }
}